// Round 3
// baseline (5263.047 us; speedup 1.0000x reference)
//
#include <hip/hip_runtime.h>
#include <cmath>

// Problem constants
constexpr int cB  = 4096;
constexpr int cT  = 45;
constexpr int cD  = 128;
constexpr int cH  = 512;
constexpr int cG  = 2048;   // 4*H
constexpr int cTp = 9;
constexpr int cKE = 640;    // enc GEMM K: 128 (input) + 512 (hidden)
constexpr int cKD = 1056;   // dec GEMM K: 513 + 512 = 1025, padded to 1056 (33*32)

// Workspace layout (float offsets)
constexpr long ofFeat = 0;                               // B*9*128
constexpr long ofWenc = ofFeat + (long)cB * cTp * 128;   // 2048*640
constexpr long ofBenc = ofWenc + (long)cG * cKE;         // 2048
constexpr long ofWdec = ofBenc + cG;                     // 2048*1056
constexpr long ofBdec = ofWdec + (long)cG * cKD;         // 2048
constexpr long ofA    = ofBdec + cG;                     // B*1056 (pack buffer)
constexpr long ofGt   = ofA + (long)cB * cKD;            // B*2048 (gates)
constexpr long ofHenc = ofGt + (long)cB * cG;            // B*512
constexpr long ofCenc = ofHenc + (long)cB * cH;          // B*512 (contiguous with Henc)
constexpr long ofXenc = ofCenc + (long)cB * cH;          // B*9*512
constexpr long ofHdec = ofXenc + (long)cB * cTp * cH;    // B*512
constexpr long ofCdec = ofHdec + (long)cB * cH;          // B*512 (contiguous with Hdec)
constexpr long ofQ    = ofCdec + (long)cB * cH;          // B*512
constexpr long ofK    = ofQ + (long)cB * cH;             // B*512
constexpr long ofV    = ofK + (long)cB * cH;             // B*512
constexpr long ofZ    = ofV + (long)cB * cH;             // B*B
constexpr long ofVT   = ofZ + (long)cB * cB;             // 512*B
constexpr long ofSt   = ofVT + (long)cH * cB;            // B*512
constexpr long wsFloats = ofSt + (long)cB * cH;          // ~75.4M floats ~ 302 MB

// ---------------------------------------------------------------------------
// RCNN front-end: one block per (batch, scale). Computes the 32-channel
// feature slice for this scale, left-padded to Tp=9, and writes it into
// feat[b][t][s*32 + c].
// ---------------------------------------------------------------------------
__global__ __launch_bounds__(256) void rcnn_kernel(
    const float* __restrict__ x,
    const float* __restrict__ w1, const float* __restrict__ b1,
    const float* __restrict__ w2, const float* __restrict__ b2,
    const float* __restrict__ w3, const float* __restrict__ b3,
    float* __restrict__ feat) {
  const int b = blockIdx.x;
  const int s = blockIdx.y;           // 0..3 -> stride s+1
  const int stride = s + 1;
  const int L  = (cT + stride - 1) / stride;  // 45,23,15,12
  const int L2 = L - 2;                       // 43,21,13,10
  const int Lp = L2 / 2;                      // 21,10, 6, 5
  const int L3 = Lp - 2;                      // 19, 8, 4, 3
  const int Lf = L3 / 2;                      //  9, 4, 2, 1
  const int pad = cTp - Lf;
  const int tid = threadIdx.x;

  __shared__ float xs[45 * 128];
  __shared__ float w1s[16 * 128];
  __shared__ float w2s[32 * 16 * 3];
  __shared__ float w3s[32 * 32 * 3];
  __shared__ float h1[16 * 45];
  __shared__ float h2[32 * 43];
  __shared__ float p2[32 * 21];
  __shared__ float h3[32 * 19];
  __shared__ float p3[32 * 9];

  for (int i = tid; i < 16 * 128; i += 256) w1s[i] = w1[s * 16 * 128 + i];
  for (int i = tid; i < 32 * 48; i += 256)  w2s[i] = w2[s * 32 * 48 + i];
  for (int i = tid; i < 32 * 96; i += 256)  w3s[i] = w3[s * 32 * 96 + i];
  for (int i = tid; i < L * 128; i += 256) {
    int l = i >> 7, d = i & 127;
    xs[i] = x[((long)b * cT + (long)l * stride) * cD + d];
  }
  __syncthreads();

  // conv1: h1[c][l] = b1 + sum_d w1[c][d]*xs[l][d]
  for (int i = tid; i < 16 * L; i += 256) {
    int c = i / L, l = i % L;
    const float* wr = &w1s[c * 128];
    const float* xr = &xs[l * 128];
    float acc = b1[s * 16 + c];
    for (int d = 0; d < 128; ++d) acc += wr[d] * xr[d];
    h1[c * 45 + l] = acc;
  }
  __syncthreads();

  // conv2 (k=3, valid): h2[c][l]
  for (int i = tid; i < 32 * L2; i += 256) {
    int c = i / L2, l = i % L2;
    const float* wr = &w2s[c * 48];
    float acc = b2[s * 32 + c];
    for (int ci = 0; ci < 16; ++ci)
      for (int kk = 0; kk < 3; ++kk)
        acc += wr[ci * 3 + kk] * h1[ci * 45 + l + kk];
    h2[c * 43 + l] = acc;
  }
  __syncthreads();

  // maxpool2
  for (int i = tid; i < 32 * Lp; i += 256) {
    int c = i / Lp, l = i % Lp;
    p2[c * 21 + l] = fmaxf(h2[c * 43 + 2 * l], h2[c * 43 + 2 * l + 1]);
  }
  __syncthreads();

  // conv3 (k=3, valid): h3[c][l]
  for (int i = tid; i < 32 * L3; i += 256) {
    int c = i / L3, l = i % L3;
    const float* wr = &w3s[c * 96];
    float acc = b3[s * 32 + c];
    for (int ci = 0; ci < 32; ++ci)
      for (int kk = 0; kk < 3; ++kk)
        acc += wr[ci * 3 + kk] * p2[ci * 21 + l + kk];
    h3[c * 19 + l] = acc;
  }
  __syncthreads();

  // maxpool2
  for (int i = tid; i < 32 * Lf; i += 256) {
    int c = i / Lf, l = i % Lf;
    p3[c * 9 + l] = fmaxf(h3[c * 19 + 2 * l], h3[c * 19 + 2 * l + 1]);
  }
  __syncthreads();

  // write feat[b][t][s*32+c] with left padding
  for (int i = tid; i < 32 * cTp; i += 256) {
    int c = i / cTp, t = i % cTp;
    float v = (t >= pad) ? p3[c * 9 + (t - pad)] : 0.0f;
    feat[((long)b * cTp + t) * 128 + s * 32 + c] = v;
  }
}

// ---------------------------------------------------------------------------
// Weight concat prep (once per launch; ws is re-poisoned every call)
// ---------------------------------------------------------------------------
__global__ void prep_enc_w(const float* __restrict__ wih, const float* __restrict__ whh,
                           const float* __restrict__ bih, const float* __restrict__ bhh,
                           float* __restrict__ W, float* __restrict__ bias) {
  long i = (long)blockIdx.x * 256 + threadIdx.x;
  if (i < (long)cG * cKE) {
    int g = (int)(i / cKE), k = (int)(i % cKE);
    W[i] = (k < 128) ? wih[(long)g * 128 + k] : whh[(long)g * 512 + (k - 128)];
  }
  if (i < cG) bias[i] = bih[i] + bhh[i];
}

__global__ void prep_dec_w(const float* __restrict__ wih, const float* __restrict__ whh,
                           const float* __restrict__ bih, const float* __restrict__ bhh,
                           float* __restrict__ W, float* __restrict__ bias) {
  long i = (long)blockIdx.x * 256 + threadIdx.x;
  if (i < (long)cG * cKD) {
    int g = (int)(i / cKD), k = (int)(i % cKD);
    float v;
    if (k < 513)       v = wih[(long)g * 513 + k];
    else if (k < 1025) v = whh[(long)g * 512 + (k - 513)];
    else               v = 0.0f;
    W[i] = v;
  }
  if (i < cG) bias[i] = bih[i] + bhh[i];
}

// ---------------------------------------------------------------------------
// Per-step input packing: A[b][:] = concat(step inputs, hidden)
// ---------------------------------------------------------------------------
__global__ void pack_enc(const float* __restrict__ feat, const float* __restrict__ h,
                         float* __restrict__ A, int t) {
  long i = (long)blockIdx.x * 256 + threadIdx.x;
  if (i >= (long)cB * cKE) return;
  int b = (int)(i / cKE), k = (int)(i % cKE);
  A[i] = (k < 128) ? feat[((long)b * cTp + t) * 128 + k]
                   : h[(long)b * cH + (k - 128)];
}

__global__ void pack_dec(const float* __restrict__ xenc, const float* __restrict__ y,
                         const float* __restrict__ h, float* __restrict__ A,
                         int t, int yidx) {
  long i = (long)blockIdx.x * 256 + threadIdx.x;
  if (i >= (long)cB * cKD) return;
  int b = (int)(i / cKD), k = (int)(i % cKD);
  float v;
  if (k < 512)        v = xenc[((long)b * cTp + t) * cH + k];
  else if (k == 512)  v = y[(long)b * cT + yidx];
  else if (k < 1025)  v = h[(long)b * cH + (k - 513)];
  else                v = 0.0f;
  A[i] = v;
}

// ---------------------------------------------------------------------------
// Generic NT GEMM: C[m][n] = alpha * sum_k A[m][k]*W[n][k] (+ bias[n])
// A: M x K row-major (lda), W: N x K row-major (ldw). M,N multiples of 64,
// K multiple of 32, rows 16B-aligned. 64x64 tile, 4x4 per thread.
// ---------------------------------------------------------------------------
__global__ __launch_bounds__(256) void gemm_nt(
    const float* __restrict__ A, int lda,
    const float* __restrict__ W, int ldw,
    const float* __restrict__ bias,
    float* __restrict__ C, int ldc,
    int K, float alpha) {
  __shared__ float As[32][68];  // [k][m], +4 pad keeps 16B alignment, spreads banks
  __shared__ float Ws[32][68];  // [k][n]
  const int tid = threadIdx.x;
  const int tx = tid & 15, ty = tid >> 4;
  const long m0 = (long)blockIdx.x * 64;
  const long n0 = (long)blockIdx.y * 64;
  const float* Ab = A + m0 * lda;
  const float* Wb = W + n0 * ldw;
  float acc[4][4] = {};

  for (int k0 = 0; k0 < K; k0 += 32) {
#pragma unroll
    for (int r = 0; r < 2; ++r) {
      int f = tid + r * 256;       // float4 index within 64x32 tile
      int row = f >> 3;            // 8 float4 per row
      int c4 = (f & 7) << 2;
      const float4 av = *reinterpret_cast<const float4*>(Ab + (long)row * lda + k0 + c4);
      As[c4 + 0][row] = av.x; As[c4 + 1][row] = av.y;
      As[c4 + 2][row] = av.z; As[c4 + 3][row] = av.w;
      const float4 wv = *reinterpret_cast<const float4*>(Wb + (long)row * ldw + k0 + c4);
      Ws[c4 + 0][row] = wv.x; Ws[c4 + 1][row] = wv.y;
      Ws[c4 + 2][row] = wv.z; Ws[c4 + 3][row] = wv.w;
    }
    __syncthreads();
#pragma unroll
    for (int k = 0; k < 32; ++k) {
      float a[4], w[4];
#pragma unroll
      for (int i = 0; i < 4; ++i) a[i] = As[k][ty * 4 + i];
#pragma unroll
      for (int j = 0; j < 4; ++j) w[j] = Ws[k][tx * 4 + j];
#pragma unroll
      for (int i = 0; i < 4; ++i)
#pragma unroll
        for (int j = 0; j < 4; ++j)
          acc[i][j] += a[i] * w[j];
    }
    __syncthreads();
  }

#pragma unroll
  for (int i = 0; i < 4; ++i) {
    long m = m0 + ty * 4 + i;
#pragma unroll
    for (int j = 0; j < 4; ++j) {
      long n = n0 + tx * 4 + j;
      float v = acc[i][j] * alpha;
      if (bias) v += bias[n];
      C[m * ldc + n] = v;
    }
  }
}

// ---------------------------------------------------------------------------
// LSTM pointwise update. Gate order (rows of W): i, f, g, o.
// ---------------------------------------------------------------------------
__global__ __launch_bounds__(256) void lstm_update(
    const float* __restrict__ Gt, float* __restrict__ h, float* __restrict__ c,
    float* __restrict__ xenc, int t) {
  long i = (long)blockIdx.x * 256 + threadIdx.x;
  if (i >= (long)cB * cH) return;
  int b = (int)(i >> 9), j = (int)(i & 511);
  const float* g = Gt + (long)b * cG;
  float ig = g[j], fg = g[cH + j], gg = g[2 * cH + j], og = g[3 * cH + j];
  float si = 1.0f / (1.0f + expf(-ig));
  float sf = 1.0f / (1.0f + expf(-fg));
  float so = 1.0f / (1.0f + expf(-og));
  float cc = sf * c[i] + si * tanhf(gg);
  float hh = so * tanhf(cc);
  c[i] = cc;
  h[i] = hh;
  if (xenc) xenc[((long)b * cTp + t) * cH + j] = hh;
}

// ---------------------------------------------------------------------------
// Row softmax over z (B x B), in place.
// ---------------------------------------------------------------------------
__global__ __launch_bounds__(256) void softmax_rows(float* __restrict__ z) {
  const int row = blockIdx.x;
  float* zr = z + (long)row * cB;
  const int tid = threadIdx.x;
  __shared__ float redm[4];
  __shared__ float reds[4];

  float mx = -1e30f;
  for (int i = tid; i < cB; i += 256) mx = fmaxf(mx, zr[i]);
  for (int off = 32; off; off >>= 1) mx = fmaxf(mx, __shfl_xor(mx, off));
  if ((tid & 63) == 0) redm[tid >> 6] = mx;
  __syncthreads();
  mx = fmaxf(fmaxf(redm[0], redm[1]), fmaxf(redm[2], redm[3]));

  float sum = 0.0f;
  for (int i = tid; i < cB; i += 256) {
    float e = expf(zr[i] - mx);
    zr[i] = e;
    sum += e;
  }
  for (int off = 32; off; off >>= 1) sum += __shfl_xor(sum, off);
  if ((tid & 63) == 0) reds[tid >> 6] = sum;
  __syncthreads();
  sum = reds[0] + reds[1] + reds[2] + reds[3];
  float inv = 1.0f / sum;
  for (int i = tid; i < cB; i += 256) zr[i] *= inv;
}

// ---------------------------------------------------------------------------
// Transpose v (B x 512) -> vT (512 x B) so beta@v reuses the NT GEMM.
// ---------------------------------------------------------------------------
__global__ __launch_bounds__(256) void transpose_v(const float* __restrict__ v,
                                                   float* __restrict__ vT) {
  __shared__ float tile[32][33];
  const int bx = blockIdx.x;  // along B/32
  const int by = blockIdx.y;  // along 512/32
  const int tx = threadIdx.x & 31, ty = threadIdx.x >> 5;  // 32x8
#pragma unroll
  for (int i = 0; i < 4; ++i)
    tile[ty + i * 8][tx] = v[(long)(bx * 32 + ty + i * 8) * cH + by * 32 + tx];
  __syncthreads();
#pragma unroll
  for (int i = 0; i < 4; ++i)
    vT[(long)(by * 32 + ty + i * 8) * cB + bx * 32 + tx] = tile[tx][ty + i * 8];
}

// ---------------------------------------------------------------------------
// Final: out[b] = sigmoid(dot(st[b], ln_w) + ln_b). One wave per row.
// ---------------------------------------------------------------------------
__global__ __launch_bounds__(256) void final_kernel(const float* __restrict__ st,
                                                    const float* __restrict__ lnw,
                                                    const float* __restrict__ lnb,
                                                    float* __restrict__ out) {
  const int wave = threadIdx.x >> 6, lane = threadIdx.x & 63;
  const int b = blockIdx.x * 4 + wave;
  const float* sr = st + (long)b * cH;
  float acc = 0.0f;
  for (int j = lane; j < cH; j += 64) acc += sr[j] * lnw[j];
  for (int off = 32; off; off >>= 1) acc += __shfl_down(acc, off);
  if (lane == 0) out[b] = 1.0f / (1.0f + expf(-(acc + lnb[0])));
}

// ---------------------------------------------------------------------------
extern "C" void kernel_launch(void* const* d_in, const int* in_sizes, int n_in,
                              void* d_out, int out_size, void* d_ws, size_t ws_size,
                              hipStream_t stream) {
  const float* x       = (const float*)d_in[0];
  const float* y       = (const float*)d_in[1];
  const float* rcnn_w1 = (const float*)d_in[2];
  const float* rcnn_b1 = (const float*)d_in[3];
  const float* rcnn_w2 = (const float*)d_in[4];
  const float* rcnn_b2 = (const float*)d_in[5];
  const float* rcnn_w3 = (const float*)d_in[6];
  const float* rcnn_b3 = (const float*)d_in[7];
  const float* enc_wih = (const float*)d_in[8];
  const float* enc_whh = (const float*)d_in[9];
  const float* enc_bih = (const float*)d_in[10];
  const float* enc_bhh = (const float*)d_in[11];
  const float* dec_wih = (const float*)d_in[12];
  const float* dec_whh = (const float*)d_in[13];
  const float* dec_bih = (const float*)d_in[14];
  const float* dec_bhh = (const float*)d_in[15];
  const float* wq      = (const float*)d_in[16];
  const float* wk      = (const float*)d_in[17];
  const float* wv      = (const float*)d_in[18];
  const float* ln_w    = (const float*)d_in[19];
  const float* ln_b    = (const float*)d_in[20];
  float* out = (float*)d_out;

  if (ws_size < (size_t)wsFloats * sizeof(float)) return;  // need ~302 MB scratch

  float* ws   = (float*)d_ws;
  float* feat = ws + ofFeat;
  float* Wenc = ws + ofWenc;
  float* benc = ws + ofBenc;
  float* Wdec = ws + ofWdec;
  float* bdec = ws + ofBdec;
  float* Abuf = ws + ofA;
  float* Gt   = ws + ofGt;
  float* henc = ws + ofHenc;
  float* cenc = ws + ofCenc;
  float* xenc = ws + ofXenc;
  float* hdec = ws + ofHdec;
  float* cdec = ws + ofCdec;
  float* q    = ws + ofQ;
  float* kb   = ws + ofK;
  float* vb   = ws + ofV;
  float* z    = ws + ofZ;
  float* vT   = ws + ofVT;
  float* st   = ws + ofSt;

  // 1. RCNN features
  rcnn_kernel<<<dim3(cB, 4), 256, 0, stream>>>(x, rcnn_w1, rcnn_b1, rcnn_w2, rcnn_b2,
                                               rcnn_w3, rcnn_b3, feat);

  // 2. Weight concat + bias sums
  prep_enc_w<<<((long)cG * cKE + 255) / 256, 256, 0, stream>>>(enc_wih, enc_whh, enc_bih,
                                                               enc_bhh, Wenc, benc);
  prep_dec_w<<<((long)cG * cKD + 255) / 256, 256, 0, stream>>>(dec_wih, dec_whh, dec_bih,
                                                               dec_bhh, Wdec, bdec);

  // 3. Encoder LSTM (h,c zero-init; ws is poisoned each call)
  hipMemsetAsync(henc, 0, (size_t)2 * cB * cH * sizeof(float), stream);  // henc+cenc
  for (int t = 0; t < cTp; ++t) {
    pack_enc<<<((long)cB * cKE + 255) / 256, 256, 0, stream>>>(feat, henc, Abuf, t);
    gemm_nt<<<dim3(cB / 64, cG / 64), 256, 0, stream>>>(Abuf, cKE, Wenc, cKE, benc,
                                                        Gt, cG, cKE, 1.0f);
    lstm_update<<<((long)cB * cH + 255) / 256, 256, 0, stream>>>(Gt, henc, cenc, xenc, t);
  }

  // 4. Decoder LSTM
  hipMemsetAsync(hdec, 0, (size_t)2 * cB * cH * sizeof(float), stream);  // hdec+cdec
  for (int t = 0; t < cTp; ++t) {
    int yidx = 4 + 5 * t;  // idx = [4,9,...,44]
    pack_dec<<<((long)cB * cKD + 255) / 256, 256, 0, stream>>>(xenc, y, hdec, Abuf, t, yidx);
    gemm_nt<<<dim3(cB / 64, cG / 64), 256, 0, stream>>>(Abuf, cKD, Wdec, cKD, bdec,
                                                        Gt, cG, cKD, 1.0f);
    lstm_update<<<((long)cB * cH + 255) / 256, 256, 0, stream>>>(Gt, hdec, cdec, nullptr, 0);
  }

  // 5. q, k, v projections (hd = hdec)
  gemm_nt<<<dim3(cB / 64, cH / 64), 256, 0, stream>>>(hdec, cH, wq, cH, nullptr, q, cH, cH, 1.0f);
  gemm_nt<<<dim3(cB / 64, cH / 64), 256, 0, stream>>>(hdec, cH, wk, cH, nullptr, kb, cH, cH, 1.0f);
  gemm_nt<<<dim3(cB / 64, cH / 64), 256, 0, stream>>>(hdec, cH, wv, cH, nullptr, vb, cH, cH, 1.0f);

  // 6. z = q@k^T / sqrt(H)
  const float alpha = 1.0f / sqrtf((float)cH);
  gemm_nt<<<dim3(cB / 64, cB / 64), 256, 0, stream>>>(q, cH, kb, cH, nullptr, z, cB, cH, alpha);

  // 7. softmax rows (z -> beta in place)
  softmax_rows<<<cB, 256, 0, stream>>>(z);

  // 8. st = beta @ v  (via v^T so the NT GEMM applies)
  transpose_v<<<dim3(cB / 32, cH / 32), 256, 0, stream>>>(vb, vT);
  gemm_nt<<<dim3(cB / 64, cH / 64), 256, 0, stream>>>(z, cB, vT, cB, nullptr, st, cH, cB, 1.0f);

  // 9. final sigmoid head
  final_kernel<<<cB / 4, 256, 0, stream>>>(st, ln_w, ln_b, out);
}

// Round 4
// 1674.803 us; speedup vs baseline: 3.1425x; 3.1425x over previous
//
#include <hip/hip_runtime.h>
#include <cmath>

// Problem constants
constexpr int cB  = 4096;
constexpr int cT  = 45;
constexpr int cD  = 128;
constexpr int cH  = 512;
constexpr int cG  = 2048;   // 4*H
constexpr int cTp = 9;
constexpr int cKE = 640;    // enc GEMM K: 128 (input) + 512 (hidden)
constexpr int cKD = 1056;   // dec GEMM K: 513 + 512 = 1025, padded to 1056

typedef __attribute__((ext_vector_type(8))) short short8;   // 8 bf16
typedef __attribute__((ext_vector_type(4))) float f32x4;

__device__ __forceinline__ short f2b(float f) {             // fp32 -> bf16 RNE
  unsigned int u = __float_as_uint(f);
  u += 0x7fff + ((u >> 16) & 1);
  return (short)(u >> 16);
}
__device__ __forceinline__ float b2f(short s) {
  return __uint_as_float(((unsigned int)(unsigned short)s) << 16);
}

// Workspace layout (float offsets; bf16 buffers occupy n/2 float slots)
constexpr long ofFeat  = 0;                                  // B*9*128 f32
constexpr long ofWencB = ofFeat  + (long)cB * cTp * 128;     // 2048*640 bf16
constexpr long ofBenc  = ofWencB + (long)cG * cKE / 2;       // 2048 f32
constexpr long ofWdecB = ofBenc  + cG;                       // 2048*1056 bf16
constexpr long ofBdec  = ofWdecB + (long)cG * cKD / 2;       // 2048 f32
constexpr long ofAB    = ofBdec  + cG;                       // B*1056 bf16 (pack buf)
constexpr long ofGt    = ofAB    + (long)cB * cKD / 2;       // B*2048 f32 (gates)
constexpr long ofHenc  = ofGt    + (long)cB * cG;            // B*512 f32
constexpr long ofCenc  = ofHenc  + (long)cB * cH;            // B*512 f32
constexpr long ofXenc  = ofCenc  + (long)cB * cH;            // B*9*512 f32
constexpr long ofHdec  = ofXenc  + (long)cB * cTp * cH;      // B*512 f32
constexpr long ofCdec  = ofHdec  + (long)cB * cH;            // B*512 f32
constexpr long ofHdecB = ofCdec  + (long)cB * cH;            // B*512 bf16
constexpr long ofWqB   = ofHdecB + (long)cB * cH / 2;        // 512*512 bf16
constexpr long ofWkB   = ofWqB   + (long)cH * cH / 2;
constexpr long ofWvB   = ofWkB   + (long)cH * cH / 2;
constexpr long ofQB    = ofWvB   + (long)cH * cH / 2;        // B*512 bf16
constexpr long ofKB    = ofQB    + (long)cB * cH / 2;
constexpr long ofVB    = ofKB    + (long)cB * cH / 2;
constexpr long ofZB    = ofVB    + (long)cB * cH / 2;        // B*B bf16 (z / beta)
constexpr long ofVT    = ofZB    + (long)cB * cB / 2;        // 512*B bf16
constexpr long ofSt    = ofVT    + (long)cH * cB / 2;        // B*512 f32
constexpr long wsFloats = ofSt   + (long)cB * cH;            // ~60.4M floats ~242 MB

// ---------------------------------------------------------------------------
// RCNN front-end: one block per (batch, scale). xs padded to stride 129 to
// kill the stride-128 bank conflict (bank = (l*128+d)%32 was d%32 for all l).
// ---------------------------------------------------------------------------
__global__ __launch_bounds__(256) void rcnn_kernel(
    const float* __restrict__ x,
    const float* __restrict__ w1, const float* __restrict__ b1,
    const float* __restrict__ w2, const float* __restrict__ b2,
    const float* __restrict__ w3, const float* __restrict__ b3,
    float* __restrict__ feat) {
  const int b = blockIdx.x;
  const int s = blockIdx.y;           // 0..3 -> stride s+1
  const int stride = s + 1;
  const int L  = (cT + stride - 1) / stride;  // 45,23,15,12
  const int L2 = L - 2;                       // 43,21,13,10
  const int Lp = L2 / 2;                      // 21,10, 6, 5
  const int L3 = Lp - 2;                      // 19, 8, 4, 3
  const int Lf = L3 / 2;                      //  9, 4, 2, 1
  const int pad = cTp - Lf;
  const int tid = threadIdx.x;

  __shared__ float xs[45 * 129];      // stride 129: bank = (l+d)%32, conflict-free
  __shared__ float w1s[16 * 128];
  __shared__ float w2s[32 * 16 * 3];
  __shared__ float w3s[32 * 32 * 3];
  __shared__ float h1[16 * 45];
  __shared__ float h2[32 * 43];
  __shared__ float p2[32 * 21];
  __shared__ float h3[32 * 19];
  __shared__ float p3[32 * 9];

  for (int i = tid; i < 16 * 128; i += 256) w1s[i] = w1[s * 16 * 128 + i];
  for (int i = tid; i < 32 * 48; i += 256)  w2s[i] = w2[s * 32 * 48 + i];
  for (int i = tid; i < 32 * 96; i += 256)  w3s[i] = w3[s * 32 * 96 + i];
  for (int i = tid; i < L * 128; i += 256) {
    int l = i >> 7, d = i & 127;
    xs[l * 129 + d] = x[((long)b * cT + (long)l * stride) * cD + d];
  }
  __syncthreads();

  // conv1: h1[c][l] = b1 + sum_d w1[c][d]*xs[l][d]
  for (int i = tid; i < 16 * L; i += 256) {
    int c = i / L, l = i % L;
    const float* wr = &w1s[c * 128];
    const float* xr = &xs[l * 129];
    float acc = b1[s * 16 + c];
    for (int d = 0; d < 128; ++d) acc += wr[d] * xr[d];
    h1[c * 45 + l] = acc;
  }
  __syncthreads();

  // conv2 (k=3, valid)
  for (int i = tid; i < 32 * L2; i += 256) {
    int c = i / L2, l = i % L2;
    const float* wr = &w2s[c * 48];
    float acc = b2[s * 32 + c];
    for (int ci = 0; ci < 16; ++ci)
      for (int kk = 0; kk < 3; ++kk)
        acc += wr[ci * 3 + kk] * h1[ci * 45 + l + kk];
    h2[c * 43 + l] = acc;
  }
  __syncthreads();

  for (int i = tid; i < 32 * Lp; i += 256) {
    int c = i / Lp, l = i % Lp;
    p2[c * 21 + l] = fmaxf(h2[c * 43 + 2 * l], h2[c * 43 + 2 * l + 1]);
  }
  __syncthreads();

  // conv3 (k=3, valid)
  for (int i = tid; i < 32 * L3; i += 256) {
    int c = i / L3, l = i % L3;
    const float* wr = &w3s[c * 96];
    float acc = b3[s * 32 + c];
    for (int ci = 0; ci < 32; ++ci)
      for (int kk = 0; kk < 3; ++kk)
        acc += wr[ci * 3 + kk] * p2[ci * 21 + l + kk];
    h3[c * 19 + l] = acc;
  }
  __syncthreads();

  for (int i = tid; i < 32 * Lf; i += 256) {
    int c = i / Lf, l = i % Lf;
    p3[c * 9 + l] = fmaxf(h3[c * 19 + 2 * l], h3[c * 19 + 2 * l + 1]);
  }
  __syncthreads();

  for (int i = tid; i < 32 * cTp; i += 256) {
    int c = i / cTp, t = i % cTp;
    float v = (t >= pad) ? p3[c * 9 + (t - pad)] : 0.0f;
    feat[((long)b * cTp + t) * 128 + s * 32 + c] = v;
  }
}

// ---------------------------------------------------------------------------
// Weight prep: concat + bf16 convert (weights are GEMM W operands)
// ---------------------------------------------------------------------------
__global__ void prep_enc_w(const float* __restrict__ wih, const float* __restrict__ whh,
                           const float* __restrict__ bih, const float* __restrict__ bhh,
                           short* __restrict__ W, float* __restrict__ bias) {
  long i = (long)blockIdx.x * 256 + threadIdx.x;
  if (i < (long)cG * cKE) {
    int g = (int)(i / cKE), k = (int)(i % cKE);
    float v = (k < 128) ? wih[(long)g * 128 + k] : whh[(long)g * 512 + (k - 128)];
    W[i] = f2b(v);
  }
  if (i < cG) bias[i] = bih[i] + bhh[i];
}

__global__ void prep_dec_w(const float* __restrict__ wih, const float* __restrict__ whh,
                           const float* __restrict__ bih, const float* __restrict__ bhh,
                           short* __restrict__ W, float* __restrict__ bias) {
  long i = (long)blockIdx.x * 256 + threadIdx.x;
  if (i < (long)cG * cKD) {
    int g = (int)(i / cKD), k = (int)(i % cKD);
    float v;
    if (k < 513)       v = wih[(long)g * 513 + k];
    else if (k < 1025) v = whh[(long)g * 512 + (k - 513)];
    else               v = 0.0f;
    W[i] = f2b(v);
  }
  if (i < cG) bias[i] = bih[i] + bhh[i];
}

__global__ void conv_f2b(const float* __restrict__ s, short* __restrict__ d, long n) {
  long i = (long)blockIdx.x * 256 + threadIdx.x;
  if (i < n) d[i] = f2b(s[i]);
}

// ---------------------------------------------------------------------------
// Per-step input packing (emit bf16 GEMM A operand)
// ---------------------------------------------------------------------------
__global__ void pack_enc(const float* __restrict__ feat, const float* __restrict__ h,
                         short* __restrict__ A, int t) {
  long i = (long)blockIdx.x * 256 + threadIdx.x;
  if (i >= (long)cB * cKE) return;
  int b = (int)(i / cKE), k = (int)(i % cKE);
  float v = (k < 128) ? feat[((long)b * cTp + t) * 128 + k]
                      : h[(long)b * cH + (k - 128)];
  A[i] = f2b(v);
}

__global__ void pack_dec(const float* __restrict__ xenc, const float* __restrict__ y,
                         const float* __restrict__ h, short* __restrict__ A,
                         int t, int yidx) {
  long i = (long)blockIdx.x * 256 + threadIdx.x;
  if (i >= (long)cB * cKD) return;
  int b = (int)(i / cKD), k = (int)(i % cKD);
  float v;
  if (k < 512)        v = xenc[((long)b * cTp + t) * cH + k];
  else if (k == 512)  v = y[(long)b * cT + yidx];
  else if (k < 1025)  v = h[(long)b * cH + (k - 513)];
  else                v = 0.0f;
  A[i] = f2b(v);
}

// ---------------------------------------------------------------------------
// bf16 MFMA NT GEMM: C[m][n] = alpha*sum_k A[m][k]*W[n][k] (+bias[n])
// A: M x K bf16 row-major, W: N x K bf16 row-major. M%128==0, N%128==0,
// K%32==0, rows 16B-aligned. 128x128 tile, 4 waves (2x2), each wave 64x64
// via 4x4 frags of v_mfma_f32_16x16x32_bf16. LDS rows padded to 40 bf16
// (80B): row bank-starts spread mod 32, <=2-way conflict (free, m136).
// C/D mapping (m89/m91): col=lane&15, row=(lane>>4)*4+reg.
// A/B frag: row|col=lane&15, k=(lane>>4)*8+elem (contiguous 16B per lane).
// ---------------------------------------------------------------------------
__global__ __launch_bounds__(256) void gemm_bf16_nt(
    const short* __restrict__ A, int lda,
    const short* __restrict__ W, int ldw,
    const float* __restrict__ bias,
    float* __restrict__ C,        // fp32 out (nullable)
    short* __restrict__ Cb,       // bf16 out (nullable)
    int ldc, int K, float alpha) {
  __shared__ short lsA[128 * 40];
  __shared__ short lsB[128 * 40];
  const int tid  = threadIdx.x;
  const int lane = tid & 63;
  const int wave = tid >> 6;
  const int wr = wave >> 1, wc = wave & 1;       // 2x2 wave grid
  const long m0 = (long)blockIdx.x * 128;
  const long n0 = (long)blockIdx.y * 128;

  f32x4 acc[4][4];
#pragma unroll
  for (int i = 0; i < 4; ++i)
#pragma unroll
    for (int j = 0; j < 4; ++j) acc[i][j] = (f32x4)0.0f;

  const int srow = tid >> 2;          // 0..63
  const int sko  = (tid & 3) * 8;     // 0,8,16,24
  const int rbase = lane & 15;
  const int kk    = (lane >> 4) * 8;

  for (int k0 = 0; k0 < K; k0 += 32) {
    __syncthreads();  // previous fragments consumed
    // stage 128x32 A and W tiles (each thread: 2 rows x 8 bf16)
    *(short8*)&lsA[srow * 40 + sko] =
        *(const short8*)&A[(m0 + srow) * (long)lda + k0 + sko];
    *(short8*)&lsA[(srow + 64) * 40 + sko] =
        *(const short8*)&A[(m0 + srow + 64) * (long)lda + k0 + sko];
    *(short8*)&lsB[srow * 40 + sko] =
        *(const short8*)&W[(n0 + srow) * (long)ldw + k0 + sko];
    *(short8*)&lsB[(srow + 64) * 40 + sko] =
        *(const short8*)&W[(n0 + srow + 64) * (long)ldw + k0 + sko];
    __syncthreads();

    short8 af[4], bf[4];
#pragma unroll
    for (int i = 0; i < 4; ++i)
      af[i] = *(const short8*)&lsA[(wr * 64 + i * 16 + rbase) * 40 + kk];
#pragma unroll
    for (int j = 0; j < 4; ++j)
      bf[j] = *(const short8*)&lsB[(wc * 64 + j * 16 + rbase) * 40 + kk];
#pragma unroll
    for (int i = 0; i < 4; ++i)
#pragma unroll
      for (int j = 0; j < 4; ++j)
        acc[i][j] = __builtin_amdgcn_mfma_f32_16x16x32_bf16(af[i], bf[j], acc[i][j], 0, 0, 0);
  }

  // epilogue
#pragma unroll
  for (int i = 0; i < 4; ++i) {
#pragma unroll
    for (int j = 0; j < 4; ++j) {
      long ncol = n0 + wc * 64 + j * 16 + (lane & 15);
      float bv = bias ? bias[ncol] : 0.0f;
#pragma unroll
      for (int r = 0; r < 4; ++r) {
        long mrow = m0 + wr * 64 + i * 16 + (lane >> 4) * 4 + r;
        float v = acc[i][j][r] * alpha + bv;
        if (C)  C[mrow * ldc + ncol] = v;
        if (Cb) Cb[mrow * ldc + ncol] = f2b(v);
      }
    }
  }
}

// ---------------------------------------------------------------------------
// LSTM pointwise update. Gate order: i, f, g, o.
// ---------------------------------------------------------------------------
__global__ __launch_bounds__(256) void lstm_update(
    const float* __restrict__ Gt, float* __restrict__ h, float* __restrict__ c,
    float* __restrict__ xenc, int t) {
  long i = (long)blockIdx.x * 256 + threadIdx.x;
  if (i >= (long)cB * cH) return;
  int b = (int)(i >> 9), j = (int)(i & 511);
  const float* g = Gt + (long)b * cG;
  float ig = g[j], fg = g[cH + j], gg = g[2 * cH + j], og = g[3 * cH + j];
  float si = 1.0f / (1.0f + expf(-ig));
  float sf = 1.0f / (1.0f + expf(-fg));
  float so = 1.0f / (1.0f + expf(-og));
  float cc = sf * c[i] + si * tanhf(gg);
  float hh = so * tanhf(cc);
  c[i] = cc;
  h[i] = hh;
  if (xenc) xenc[((long)b * cTp + t) * cH + j] = hh;
}

// ---------------------------------------------------------------------------
// Row softmax over bf16 z (B x B), in place (z -> beta). 16 elems/thread
// cached in registers.
// ---------------------------------------------------------------------------
__global__ __launch_bounds__(256) void softmax_b(short* __restrict__ zb) {
  const int row = blockIdx.x;
  short* zr = zb + (long)row * cB;
  const int tid = threadIdx.x;
  __shared__ float red[4];

  float e[16];
  float mx = -1e30f;
#pragma unroll
  for (int idx = 0; idx < 16; ++idx) {
    float v = b2f(zr[tid + idx * 256]);
    e[idx] = v;
    mx = fmaxf(mx, v);
  }
  for (int off = 32; off; off >>= 1) mx = fmaxf(mx, __shfl_xor(mx, off));
  if ((tid & 63) == 0) red[tid >> 6] = mx;
  __syncthreads();
  mx = fmaxf(fmaxf(red[0], red[1]), fmaxf(red[2], red[3]));
  __syncthreads();

  float sum = 0.0f;
#pragma unroll
  for (int idx = 0; idx < 16; ++idx) {
    float ev = expf(e[idx] - mx);
    e[idx] = ev;
    sum += ev;
  }
  for (int off = 32; off; off >>= 1) sum += __shfl_xor(sum, off);
  if ((tid & 63) == 0) red[tid >> 6] = sum;
  __syncthreads();
  sum = red[0] + red[1] + red[2] + red[3];
  float inv = 1.0f / sum;
#pragma unroll
  for (int idx = 0; idx < 16; ++idx) zr[tid + idx * 256] = f2b(e[idx] * inv);
}

// ---------------------------------------------------------------------------
// Transpose bf16 v (B x 512) -> vT (512 x B)
// ---------------------------------------------------------------------------
__global__ __launch_bounds__(256) void transpose_v16(const short* __restrict__ v,
                                                     short* __restrict__ vT) {
  __shared__ short tile[32][33];
  const int bx = blockIdx.x;  // along B/32
  const int by = blockIdx.y;  // along 512/32
  const int tx = threadIdx.x & 31, ty = threadIdx.x >> 5;  // 32x8
#pragma unroll
  for (int i = 0; i < 4; ++i)
    tile[ty + i * 8][tx] = v[(long)(bx * 32 + ty + i * 8) * cH + by * 32 + tx];
  __syncthreads();
#pragma unroll
  for (int i = 0; i < 4; ++i)
    vT[(long)(by * 32 + ty + i * 8) * cB + bx * 32 + tx] = tile[tx][ty + i * 8];
}

// ---------------------------------------------------------------------------
// Final: out[b] = sigmoid(dot(st[b], ln_w) + ln_b). One wave per row.
// ---------------------------------------------------------------------------
__global__ __launch_bounds__(256) void final_kernel(const float* __restrict__ st,
                                                    const float* __restrict__ lnw,
                                                    const float* __restrict__ lnb,
                                                    float* __restrict__ out) {
  const int wave = threadIdx.x >> 6, lane = threadIdx.x & 63;
  const int b = blockIdx.x * 4 + wave;
  const float* sr = st + (long)b * cH;
  float acc = 0.0f;
  for (int j = lane; j < cH; j += 64) acc += sr[j] * lnw[j];
  for (int off = 32; off; off >>= 1) acc += __shfl_down(acc, off);
  if (lane == 0) out[b] = 1.0f / (1.0f + expf(-(acc + lnb[0])));
}

// ---------------------------------------------------------------------------
extern "C" void kernel_launch(void* const* d_in, const int* in_sizes, int n_in,
                              void* d_out, int out_size, void* d_ws, size_t ws_size,
                              hipStream_t stream) {
  const float* x       = (const float*)d_in[0];
  const float* y       = (const float*)d_in[1];
  const float* rcnn_w1 = (const float*)d_in[2];
  const float* rcnn_b1 = (const float*)d_in[3];
  const float* rcnn_w2 = (const float*)d_in[4];
  const float* rcnn_b2 = (const float*)d_in[5];
  const float* rcnn_w3 = (const float*)d_in[6];
  const float* rcnn_b3 = (const float*)d_in[7];
  const float* enc_wih = (const float*)d_in[8];
  const float* enc_whh = (const float*)d_in[9];
  const float* enc_bih = (const float*)d_in[10];
  const float* enc_bhh = (const float*)d_in[11];
  const float* dec_wih = (const float*)d_in[12];
  const float* dec_whh = (const float*)d_in[13];
  const float* dec_bih = (const float*)d_in[14];
  const float* dec_bhh = (const float*)d_in[15];
  const float* wq      = (const float*)d_in[16];
  const float* wk      = (const float*)d_in[17];
  const float* wv      = (const float*)d_in[18];
  const float* ln_w    = (const float*)d_in[19];
  const float* ln_b    = (const float*)d_in[20];
  float* out = (float*)d_out;

  if (ws_size < (size_t)wsFloats * sizeof(float)) return;  // ~242 MB scratch

  float* ws    = (float*)d_ws;
  float* feat  = ws + ofFeat;
  short* WencB = (short*)(ws + ofWencB);
  float* benc  = ws + ofBenc;
  short* WdecB = (short*)(ws + ofWdecB);
  float* bdec  = ws + ofBdec;
  short* AB    = (short*)(ws + ofAB);
  float* Gt    = ws + ofGt;
  float* henc  = ws + ofHenc;
  float* xenc  = ws + ofXenc;
  float* hdec  = ws + ofHdec;
  float* cdec  = ws + ofCdec;
  short* hdecB = (short*)(ws + ofHdecB);
  short* wqB   = (short*)(ws + ofWqB);
  short* wkB   = (short*)(ws + ofWkB);
  short* wvB   = (short*)(ws + ofWvB);
  short* qB    = (short*)(ws + ofQB);
  short* kB    = (short*)(ws + ofKB);
  short* vB    = (short*)(ws + ofVB);
  short* zB    = (short*)(ws + ofZB);
  short* vT    = (short*)(ws + ofVT);
  float* st    = ws + ofSt;
  float* cenc  = ws + ofCenc;

  // 1. RCNN features
  rcnn_kernel<<<dim3(cB, 4), 256, 0, stream>>>(x, rcnn_w1, rcnn_b1, rcnn_w2, rcnn_b2,
                                               rcnn_w3, rcnn_b3, feat);

  // 2. Weight prep (concat + bf16)
  prep_enc_w<<<((long)cG * cKE + 255) / 256, 256, 0, stream>>>(enc_wih, enc_whh, enc_bih,
                                                               enc_bhh, WencB, benc);
  prep_dec_w<<<((long)cG * cKD + 255) / 256, 256, 0, stream>>>(dec_wih, dec_whh, dec_bih,
                                                               dec_bhh, WdecB, bdec);
  conv_f2b<<<((long)cH * cH + 255) / 256, 256, 0, stream>>>(wq, wqB, (long)cH * cH);
  conv_f2b<<<((long)cH * cH + 255) / 256, 256, 0, stream>>>(wk, wkB, (long)cH * cH);
  conv_f2b<<<((long)cH * cH + 255) / 256, 256, 0, stream>>>(wv, wvB, (long)cH * cH);

  // 3. Encoder LSTM
  hipMemsetAsync(henc, 0, (size_t)2 * cB * cH * sizeof(float), stream);  // henc+cenc
  for (int t = 0; t < cTp; ++t) {
    pack_enc<<<((long)cB * cKE + 255) / 256, 256, 0, stream>>>(feat, henc, AB, t);
    gemm_bf16_nt<<<dim3(cB / 128, cG / 128), 256, 0, stream>>>(
        AB, cKE, WencB, cKE, benc, Gt, nullptr, cG, cKE, 1.0f);
    lstm_update<<<((long)cB * cH + 255) / 256, 256, 0, stream>>>(Gt, henc, cenc, xenc, t);
  }

  // 4. Decoder LSTM
  hipMemsetAsync(hdec, 0, (size_t)2 * cB * cH * sizeof(float), stream);  // hdec+cdec
  for (int t = 0; t < cTp; ++t) {
    int yidx = 4 + 5 * t;  // idx = [4,9,...,44]
    pack_dec<<<((long)cB * cKD + 255) / 256, 256, 0, stream>>>(xenc, y, hdec, AB, t, yidx);
    gemm_bf16_nt<<<dim3(cB / 128, cG / 128), 256, 0, stream>>>(
        AB, cKD, WdecB, cKD, bdec, Gt, nullptr, cG, cKD, 1.0f);
    lstm_update<<<((long)cB * cH + 255) / 256, 256, 0, stream>>>(Gt, hdec, cdec, nullptr, 0);
  }

  // 5. q, k, v projections (bf16 outputs)
  conv_f2b<<<((long)cB * cH + 255) / 256, 256, 0, stream>>>(hdec, hdecB, (long)cB * cH);
  gemm_bf16_nt<<<dim3(cB / 128, cH / 128), 256, 0, stream>>>(
      hdecB, cH, wqB, cH, nullptr, nullptr, qB, cH, cH, 1.0f);
  gemm_bf16_nt<<<dim3(cB / 128, cH / 128), 256, 0, stream>>>(
      hdecB, cH, wkB, cH, nullptr, nullptr, kB, cH, cH, 1.0f);
  gemm_bf16_nt<<<dim3(cB / 128, cH / 128), 256, 0, stream>>>(
      hdecB, cH, wvB, cH, nullptr, nullptr, vB, cH, cH, 1.0f);

  // 6. z = q@k^T / sqrt(H)  (bf16 out)
  const float alpha = 1.0f / sqrtf((float)cH);
  gemm_bf16_nt<<<dim3(cB / 128, cB / 128), 256, 0, stream>>>(
      qB, cH, kB, cH, nullptr, nullptr, zB, cB, cH, alpha);

  // 7. softmax rows in place (z -> beta)
  softmax_b<<<cB, 256, 0, stream>>>(zB);

  // 8. st = beta @ v (via bf16 v^T)
  transpose_v16<<<dim3(cB / 32, cH / 32), 256, 0, stream>>>(vB, vT);
  gemm_bf16_nt<<<dim3(cB / 128, cH / 128), 256, 0, stream>>>(
      zB, cB, vT, cB, nullptr, st, nullptr, cH, cB, 1.0f);

  // 9. final sigmoid head
  final_kernel<<<cB / 4, 256, 0, stream>>>(st, ln_w, ln_b, out);
}

// Round 10
// 1474.109 us; speedup vs baseline: 3.5703x; 1.1361x over previous
//
#include <hip/hip_runtime.h>
#include <cmath>

// Problem constants
constexpr int cB  = 4096;
constexpr int cT  = 45;
constexpr int cD  = 128;
constexpr int cH  = 512;
constexpr int cG  = 2048;   // 4*H
constexpr int cTp = 9;
constexpr int cKE = 640;    // enc GEMM K: 128 (feat) + 512 (hidden)
constexpr int cKD = 1024;   // dec GEMM K: 512 (xenc) + 512 (hidden); y folded into lstm_update

typedef __attribute__((ext_vector_type(8))) short short8;   // 8 bf16
typedef __attribute__((ext_vector_type(4))) float f32x4;

__device__ __forceinline__ short f2b(float f) {             // fp32 -> bf16 RNE
  unsigned int u = __float_as_uint(f);
  u += 0x7fff + ((u >> 16) & 1);
  return (short)(u >> 16);
}
__device__ __forceinline__ float b2f(short s) {
  return __uint_as_float(((unsigned int)(unsigned short)s) << 16);
}

// Workspace layout (float offsets; bf16 buffers use n/2 float slots)
constexpr long ofFeatB = 0;                                   // B*9*128 bf16
constexpr long ofWencB = ofFeatB + (long)cB * cTp * 128 / 2;  // 2048*640 bf16
constexpr long ofBenc  = ofWencB + (long)cG * cKE / 2;        // 2048 f32
constexpr long ofWdecB = ofBenc  + cG;                        // 2048*1024 bf16
constexpr long ofBdec  = ofWdecB + (long)cG * cKD / 2;        // 2048 f32
constexpr long ofWy    = ofBdec  + cG;                        // 2048 f32 (dec_wih col 512)
constexpr long ofGt    = ofWy    + cG;                        // B*2048 f32 (gates)
constexpr long ofCenc  = ofGt    + (long)cB * cG;             // B*512 f32
constexpr long ofHencB = ofCenc  + (long)cB * cH;             // B*512 bf16
constexpr long ofXencB = ofHencB + (long)cB * cH / 2;         // B*9*512 bf16
constexpr long ofCdec  = ofXencB + (long)cB * cTp * cH / 2;   // B*512 f32
constexpr long ofHdecB = ofCdec  + (long)cB * cH;             // B*512 bf16
constexpr long ofWqB   = ofHdecB + (long)cB * cH / 2;         // 512*512 bf16
constexpr long ofWkB   = ofWqB   + (long)cH * cH / 2;
constexpr long ofWvB   = ofWkB   + (long)cH * cH / 2;
constexpr long ofQB    = ofWvB   + (long)cH * cH / 2;         // B*512 bf16
constexpr long ofKB    = ofQB    + (long)cB * cH / 2;
constexpr long ofVB    = ofKB    + (long)cB * cH / 2;
constexpr long ofZB    = ofVB    + (long)cB * cH / 2;         // B*B bf16 (z/beta)
constexpr long ofVT    = ofZB    + (long)cB * cB / 2;         // 512*B bf16
constexpr long ofSt    = ofVT    + (long)cH * cB / 2;         // B*512 f32
constexpr long wsFloats = ofSt   + (long)cB * cH;             // ~43.3M floats ~173 MB

// ---------------------------------------------------------------------------
// RCNN front-end, vectorized. One block per (batch, scale).
// All dot products run on float4 LDS reads; intermediates stored [l][c]
// (transposed) so conv2/conv3 inner loops are contiguous over channels.
// LDS regions aliased (xs->w3r+h3t, w1s->h2t) to fit 44.7 KB -> 3 blocks/CU.
// Emits bf16 feat directly (GEMM A operand).
// ---------------------------------------------------------------------------
__global__ __launch_bounds__(256) void rcnn_kernel(
    const float* __restrict__ x,
    const float* __restrict__ w1, const float* __restrict__ b1,
    const float* __restrict__ w2, const float* __restrict__ b2,
    const float* __restrict__ w3, const float* __restrict__ b3,
    short* __restrict__ featB) {
  const int b = blockIdx.x;
  const int s = blockIdx.y;           // 0..3 -> stride s+1
  const int stride = s + 1;
  const int L  = (cT + stride - 1) / stride;  // 45,23,15,12
  const int L2 = L - 2;                       // 43,21,13,10
  const int Lp = L2 / 2;                      // 21,10, 6, 5
  const int L3 = Lp - 2;                      // 19, 8, 4, 3
  const int Lf = L3 / 2;                      //  9, 4, 2, 1
  const int pad = cTp - Lf;
  const int tid = threadIdx.x;

  // one shared pool with aliasing
  __shared__ float smem[11180];
  float* xs  = smem;            // [45][132]  5940  (dead after conv1)
  float* w1s = smem + 5940;     // [16][128]  2048  (dead after conv1)
  float* w2r = smem + 7988;     // [32][3][16] 1536
  float* h1t = smem + 9524;     // [45][20]    900
  float* p2t = smem + 10424;    // [21][36]    756
  float* w3r = smem;            // alias xs: [32][3][32] 3072
  float* h3t = smem + 3072;     // alias xs: [19][36]     684
  float* h2t = smem + 5940;     // alias w1s: [43][36]   1548

  // stage inputs
  for (int i = tid; i < L * 128; i += 256) {
    int l = i >> 7, d = i & 127;
    xs[l * 132 + d] = x[((long)b * cT + (long)l * stride) * cD + d];
  }
  for (int i = tid; i < 16 * 128; i += 256) w1s[i] = w1[s * 2048 + i];
  for (int i = tid; i < 32 * 48; i += 256) {
    int c = i / 48, r = i % 48, ci = r / 3, kk = r % 3;
    w2r[(c * 3 + kk) * 16 + ci] = w2[s * 1536 + i];
  }
  __syncthreads();

  // conv1: h1t[l][c] = b1[c] + sum_d w1[c][d]*xs[l][d]   (float4 over d)
  for (int i = tid; i < 16 * L; i += 256) {
    int c = i / L, l = i % L;
    const float4* xr = (const float4*)&xs[l * 132];
    const float4* wr = (const float4*)&w1s[c * 128];
    float acc = b1[s * 16 + c];
#pragma unroll
    for (int d4 = 0; d4 < 32; ++d4) {
      float4 xv = xr[d4], wv = wr[d4];
      acc += xv.x * wv.x + xv.y * wv.y + xv.z * wv.z + xv.w * wv.w;
    }
    h1t[l * 20 + c] = acc;
  }
  __syncthreads();

  // load w3 rearranged into xs region (xs dead) ; conv2 in parallel
  for (int i = tid; i < 32 * 96; i += 256) {
    int c = i / 96, r = i % 96, ci = r / 3, kk = r % 3;
    w3r[(c * 3 + kk) * 32 + ci] = w3[s * 3072 + i];
  }
  // conv2: h2t[l][c] = b2[c] + sum_{ci,kk} w2[c][ci][kk]*h1t[l+kk][ci]
  for (int i = tid; i < 32 * L2; i += 256) {
    int c = i / L2, l = i % L2;
    float acc = b2[s * 32 + c];
#pragma unroll
    for (int kk = 0; kk < 3; ++kk) {
      const float4* hp = (const float4*)&h1t[(l + kk) * 20];
      const float4* wp = (const float4*)&w2r[(c * 3 + kk) * 16];
#pragma unroll
      for (int g = 0; g < 4; ++g) {
        float4 hv = hp[g], wv = wp[g];
        acc += hv.x * wv.x + hv.y * wv.y + hv.z * wv.z + hv.w * wv.w;
      }
    }
    h2t[l * 36 + c] = acc;
  }
  __syncthreads();

  // maxpool2: p2t[l][c]
  for (int i = tid; i < 32 * Lp; i += 256) {
    int l = i >> 5, c = i & 31;
    p2t[l * 36 + c] = fmaxf(h2t[(2 * l) * 36 + c], h2t[(2 * l + 1) * 36 + c]);
  }
  __syncthreads();

  // conv3: h3t[l][c]
  for (int i = tid; i < 32 * L3; i += 256) {
    int c = i / L3, l = i % L3;
    float acc = b3[s * 32 + c];
#pragma unroll
    for (int kk = 0; kk < 3; ++kk) {
      const float4* pp = (const float4*)&p2t[(l + kk) * 36];
      const float4* wp = (const float4*)&w3r[(c * 3 + kk) * 32];
#pragma unroll
      for (int g = 0; g < 8; ++g) {
        float4 pv = pp[g], wv = wp[g];
        acc += pv.x * wv.x + pv.y * wv.y + pv.z * wv.z + pv.w * wv.w;
      }
    }
    h3t[l * 36 + c] = acc;
  }
  __syncthreads();

  // maxpool3 + left-pad + bf16 write
  for (int i = tid; i < 32 * cTp; i += 256) {
    int c = i / cTp, t = i % cTp;
    float v = 0.0f;
    if (t >= pad) {
      int l = t - pad;
      v = fmaxf(h3t[(2 * l) * 36 + c], h3t[(2 * l + 1) * 36 + c]);
    }
    featB[((long)b * cTp + t) * 128 + s * 32 + c] = f2b(v);
  }
}

// ---------------------------------------------------------------------------
// Weight prep: concat + bf16 convert
// ---------------------------------------------------------------------------
__global__ void prep_enc_w(const float* __restrict__ wih, const float* __restrict__ whh,
                           const float* __restrict__ bih, const float* __restrict__ bhh,
                           short* __restrict__ W, float* __restrict__ bias) {
  long i = (long)blockIdx.x * 256 + threadIdx.x;
  if (i < (long)cG * cKE) {
    int g = (int)(i / cKE), k = (int)(i % cKE);
    float v = (k < 128) ? wih[(long)g * 128 + k] : whh[(long)g * 512 + (k - 128)];
    W[i] = f2b(v);
  }
  if (i < cG) bias[i] = bih[i] + bhh[i];
}

__global__ void prep_dec_w(const float* __restrict__ wih, const float* __restrict__ whh,
                           const float* __restrict__ bih, const float* __restrict__ bhh,
                           short* __restrict__ W, float* __restrict__ bias,
                           float* __restrict__ wy) {
  long i = (long)blockIdx.x * 256 + threadIdx.x;
  if (i < (long)cG * cKD) {
    int g = (int)(i / cKD), k = (int)(i % cKD);
    float v = (k < 512) ? wih[(long)g * 513 + k] : whh[(long)g * 512 + (k - 512)];
    W[i] = f2b(v);
  }
  if (i < cG) {
    bias[i] = bih[i] + bhh[i];
    wy[i] = wih[i * 513 + 512];    // y column, applied in lstm_update (f32)
  }
}

__global__ void conv_f2b(const float* __restrict__ s, short* __restrict__ d, long n) {
  long i = (long)blockIdx.x * 256 + threadIdx.x;
  if (i < n) d[i] = f2b(s[i]);
}

// ---------------------------------------------------------------------------
// bf16 MFMA NT GEMM, m97-style staging: global_load_lds width=16, linear LDS
// [128][32] bf16 per operand (lane l -> LDS byte base + l*16, per m104 rule).
// Dual-source A: k in [0,K1) reads A1 (lda1), k in [K1,K) reads A2 (lda2).
// K1, K multiples of 32. C[m][n] = alpha*sum_k A[m][k]*W[n][k] (+bias[n]).
// 128x128 tile, 4 waves (2x2), 4x4 frags of v_mfma_f32_16x16x32_bf16.
// C/D mapping (m89/m91): col=lane&15, row=(lane>>4)*4+reg.
// ---------------------------------------------------------------------------
__global__ __launch_bounds__(256) void gemm_bf16_nt(
    const short* __restrict__ A1, int lda1, int K1,
    const short* __restrict__ A2, int lda2,
    const short* __restrict__ W, int ldw,
    const float* __restrict__ bias,
    float* __restrict__ C,        // fp32 out (nullable)
    short* __restrict__ Cb,       // bf16 out (nullable)
    int ldc, int K, float alpha) {
  __shared__ short lsA[128 * 32];
  __shared__ short lsB[128 * 32];
  const int tid  = threadIdx.x;
  const int lane = tid & 63;
  const int wave = tid >> 6;
  const int wr = wave >> 1, wc = wave & 1;       // 2x2 wave grid
  const long m0 = (long)blockIdx.x * 128;
  const long n0 = (long)blockIdx.y * 128;

  f32x4 acc[4][4];
#pragma unroll
  for (int i = 0; i < 4; ++i)
#pragma unroll
    for (int j = 0; j < 4; ++j) acc[i][j] = (f32x4)0.0f;

  // staging geometry: wave stages rows [wave*32, wave*32+32) of each operand
  // in two 16-row segments; lane l covers row seg+l/4, 16B chunk l%4.
  const int segrow = lane >> 2;        // 0..15
  const int chunk  = (lane & 3) * 8;   // bf16 elem offset within row
  const int rbase  = lane & 15;
  const int kk     = (lane >> 4) * 8;

  for (int k0 = 0; k0 < K; k0 += 32) {
    const short* Ab; long alda; int acol;
    if (k0 < K1) { Ab = A1; alda = lda1; acol = k0; }
    else         { Ab = A2; alda = lda2; acol = k0 - K1; }
    __syncthreads();  // previous tile's fragments consumed
#pragma unroll
    for (int cs = 0; cs < 2; ++cs) {
      int r = wave * 32 + cs * 16 + segrow;
      const short* ga = Ab + (m0 + r) * alda + acol + chunk;
      __builtin_amdgcn_global_load_lds(
          (const __attribute__((address_space(1))) void*)ga,
          (__attribute__((address_space(3))) void*)&lsA[(wave * 32 + cs * 16) * 32],
          16, 0, 0);
      const short* gw = W + (n0 + r) * (long)ldw + k0 + chunk;
      __builtin_amdgcn_global_load_lds(
          (const __attribute__((address_space(1))) void*)gw,
          (__attribute__((address_space(3))) void*)&lsB[(wave * 32 + cs * 16) * 32],
          16, 0, 0);
    }
    __syncthreads();  // compiler drains vmcnt(0) before this barrier

    short8 af[4], bf4[4];
#pragma unroll
    for (int i = 0; i < 4; ++i)
      af[i] = *(const short8*)&lsA[(wr * 64 + i * 16 + rbase) * 32 + kk];
#pragma unroll
    for (int j = 0; j < 4; ++j)
      bf4[j] = *(const short8*)&lsB[(wc * 64 + j * 16 + rbase) * 32 + kk];
#pragma unroll
    for (int i = 0; i < 4; ++i)
#pragma unroll
      for (int j = 0; j < 4; ++j)
        acc[i][j] = __builtin_amdgcn_mfma_f32_16x16x32_bf16(af[i], bf4[j], acc[i][j], 0, 0, 0);
  }

  // epilogue
#pragma unroll
  for (int i = 0; i < 4; ++i) {
#pragma unroll
    for (int j = 0; j < 4; ++j) {
      long ncol = n0 + wc * 64 + j * 16 + (lane & 15);
      float bv = bias ? bias[ncol] : 0.0f;
#pragma unroll
      for (int r = 0; r < 4; ++r) {
        long mrow = m0 + wr * 64 + i * 16 + (lane >> 4) * 4 + r;
        float v = acc[i][j][r] * alpha + bv;
        if (C)  C[mrow * ldc + ncol] = v;
        if (Cb) Cb[mrow * ldc + ncol] = f2b(v);
      }
    }
  }
}

// ---------------------------------------------------------------------------
// LSTM pointwise update. Gate order: i, f, g, o. Writes bf16 h (GEMM operand),
// f32 c, optional bf16 xenc slice, optional y rank-1 gate correction (dec).
// ---------------------------------------------------------------------------
__global__ __launch_bounds__(256) void lstm_update(
    const float* __restrict__ Gt, float* __restrict__ c, short* __restrict__ hB,
    short* __restrict__ xB, int t,
    const float* __restrict__ y, int yidx, const float* __restrict__ wy) {
  long i = (long)blockIdx.x * 256 + threadIdx.x;
  if (i >= (long)cB * cH) return;
  int b = (int)(i >> 9), j = (int)(i & 511);
  const float* g = Gt + (long)b * cG;
  float ig = g[j], fg = g[cH + j], gg = g[2 * cH + j], og = g[3 * cH + j];
  if (y) {
    float yb = y[(long)b * cT + yidx];
    ig += yb * wy[j];
    fg += yb * wy[cH + j];
    gg += yb * wy[2 * cH + j];
    og += yb * wy[3 * cH + j];
  }
  float si = 1.0f / (1.0f + expf(-ig));
  float sf = 1.0f / (1.0f + expf(-fg));
  float so = 1.0f / (1.0f + expf(-og));
  float cc = sf * c[i] + si * tanhf(gg);
  float hh = so * tanhf(cc);
  c[i] = cc;
  short hb = f2b(hh);
  hB[i] = hb;
  if (xB) xB[((long)b * cTp + t) * cH + j] = hb;
}

// ---------------------------------------------------------------------------
// Row softmax over bf16 z (B x B), in place (z -> beta).
// ---------------------------------------------------------------------------
__global__ __launch_bounds__(256) void softmax_b(short* __restrict__ zb) {
  const int row = blockIdx.x;
  short* zr = zb + (long)row * cB;
  const int tid = threadIdx.x;
  __shared__ float red[4];

  float e[16];
  float mx = -1e30f;
#pragma unroll
  for (int idx = 0; idx < 16; ++idx) {
    float v = b2f(zr[tid + idx * 256]);
    e[idx] = v;
    mx = fmaxf(mx, v);
  }
  for (int off = 32; off; off >>= 1) mx = fmaxf(mx, __shfl_xor(mx, off));
  if ((tid & 63) == 0) red[tid >> 6] = mx;
  __syncthreads();
  mx = fmaxf(fmaxf(red[0], red[1]), fmaxf(red[2], red[3]));
  __syncthreads();

  float sum = 0.0f;
#pragma unroll
  for (int idx = 0; idx < 16; ++idx) {
    float ev = expf(e[idx] - mx);
    e[idx] = ev;
    sum += ev;
  }
  for (int off = 32; off; off >>= 1) sum += __shfl_xor(sum, off);
  if ((tid & 63) == 0) red[tid >> 6] = sum;
  __syncthreads();
  sum = red[0] + red[1] + red[2] + red[3];
  float inv = 1.0f / sum;
#pragma unroll
  for (int idx = 0; idx < 16; ++idx) zr[tid + idx * 256] = f2b(e[idx] * inv);
}

// ---------------------------------------------------------------------------
// Transpose bf16 v (B x 512) -> vT (512 x B)
// ---------------------------------------------------------------------------
__global__ __launch_bounds__(256) void transpose_v16(const short* __restrict__ v,
                                                     short* __restrict__ vT) {
  __shared__ short tile[32][33];
  const int bx = blockIdx.x;  // along B/32
  const int by = blockIdx.y;  // along 512/32
  const int tx = threadIdx.x & 31, ty = threadIdx.x >> 5;  // 32x8
#pragma unroll
  for (int i = 0; i < 4; ++i)
    tile[ty + i * 8][tx] = v[(long)(bx * 32 + ty + i * 8) * cH + by * 32 + tx];
  __syncthreads();
#pragma unroll
  for (int i = 0; i < 4; ++i)
    vT[(long)(by * 32 + ty + i * 8) * cB + bx * 32 + tx] = tile[tx][ty + i * 8];
}

// ---------------------------------------------------------------------------
// Final: out[b] = sigmoid(dot(st[b], ln_w) + ln_b). One wave per row.
// ---------------------------------------------------------------------------
__global__ __launch_bounds__(256) void final_kernel(const float* __restrict__ st,
                                                    const float* __restrict__ lnw,
                                                    const float* __restrict__ lnb,
                                                    float* __restrict__ out) {
  const int wave = threadIdx.x >> 6, lane = threadIdx.x & 63;
  const int b = blockIdx.x * 4 + wave;
  const float* sr = st + (long)b * cH;
  float acc = 0.0f;
  for (int j = lane; j < cH; j += 64) acc += sr[j] * lnw[j];
  for (int off = 32; off; off >>= 1) acc += __shfl_down(acc, off);
  if (lane == 0) out[b] = 1.0f / (1.0f + expf(-(acc + lnb[0])));
}

// ---------------------------------------------------------------------------
extern "C" void kernel_launch(void* const* d_in, const int* in_sizes, int n_in,
                              void* d_out, int out_size, void* d_ws, size_t ws_size,
                              hipStream_t stream) {
  const float* x       = (const float*)d_in[0];
  const float* y       = (const float*)d_in[1];
  const float* rcnn_w1 = (const float*)d_in[2];
  const float* rcnn_b1 = (const float*)d_in[3];
  const float* rcnn_w2 = (const float*)d_in[4];
  const float* rcnn_b2 = (const float*)d_in[5];
  const float* rcnn_w3 = (const float*)d_in[6];
  const float* rcnn_b3 = (const float*)d_in[7];
  const float* enc_wih = (const float*)d_in[8];
  const float* enc_whh = (const float*)d_in[9];
  const float* enc_bih = (const float*)d_in[10];
  const float* enc_bhh = (const float*)d_in[11];
  const float* dec_wih = (const float*)d_in[12];
  const float* dec_whh = (const float*)d_in[13];
  const float* dec_bih = (const float*)d_in[14];
  const float* dec_bhh = (const float*)d_in[15];
  const float* wq      = (const float*)d_in[16];
  const float* wk      = (const float*)d_in[17];
  const float* wv      = (const float*)d_in[18];
  const float* ln_w    = (const float*)d_in[19];
  const float* ln_b    = (const float*)d_in[20];
  float* out = (float*)d_out;

  if (ws_size < (size_t)wsFloats * sizeof(float)) return;  // ~173 MB scratch

  float* ws    = (float*)d_ws;
  short* featB = (short*)(ws + ofFeatB);
  short* WencB = (short*)(ws + ofWencB);
  float* benc  = ws + ofBenc;
  short* WdecB = (short*)(ws + ofWdecB);
  float* bdec  = ws + ofBdec;
  float* wy    = ws + ofWy;
  float* Gt    = ws + ofGt;
  float* cenc  = ws + ofCenc;
  short* hencB = (short*)(ws + ofHencB);
  short* xencB = (short*)(ws + ofXencB);
  float* cdec  = ws + ofCdec;
  short* hdecB = (short*)(ws + ofHdecB);
  short* wqB   = (short*)(ws + ofWqB);
  short* wkB   = (short*)(ws + ofWkB);
  short* wvB   = (short*)(ws + ofWvB);
  short* qB    = (short*)(ws + ofQB);
  short* kB    = (short*)(ws + ofKB);
  short* vB    = (short*)(ws + ofVB);
  short* zB    = (short*)(ws + ofZB);
  short* vT    = (short*)(ws + ofVT);
  float* st    = ws + ofSt;

  // 1. RCNN features (bf16 out)
  rcnn_kernel<<<dim3(cB, 4), 256, 0, stream>>>(x, rcnn_w1, rcnn_b1, rcnn_w2, rcnn_b2,
                                               rcnn_w3, rcnn_b3, featB);

  // 2. Weight prep
  prep_enc_w<<<((long)cG * cKE + 255) / 256, 256, 0, stream>>>(enc_wih, enc_whh, enc_bih,
                                                               enc_bhh, WencB, benc);
  prep_dec_w<<<((long)cG * cKD + 255) / 256, 256, 0, stream>>>(dec_wih, dec_whh, dec_bih,
                                                               dec_bhh, WdecB, bdec, wy);
  conv_f2b<<<((long)cH * cH + 255) / 256, 256, 0, stream>>>(wq, wqB, (long)cH * cH);
  conv_f2b<<<((long)cH * cH + 255) / 256, 256, 0, stream>>>(wk, wkB, (long)cH * cH);
  conv_f2b<<<((long)cH * cH + 255) / 256, 256, 0, stream>>>(wv, wvB, (long)cH * cH);

  // 3. Encoder LSTM (dual-source GEMM reads featB + hencB directly)
  hipMemsetAsync(cenc, 0, (size_t)cB * cH * sizeof(float), stream);
  hipMemsetAsync(hencB, 0, (size_t)cB * cH * sizeof(short), stream);
  for (int t = 0; t < cTp; ++t) {
    gemm_bf16_nt<<<dim3(cB / 128, cG / 128), 256, 0, stream>>>(
        featB + t * 128, cTp * 128, 128, hencB, cH,
        WencB, cKE, benc, Gt, nullptr, cG, cKE, 1.0f);
    lstm_update<<<((long)cB * cH + 255) / 256, 256, 0, stream>>>(
        Gt, cenc, hencB, xencB, t, nullptr, 0, nullptr);
  }

  // 4. Decoder LSTM (y folded in via wy rank-1 update)
  hipMemsetAsync(cdec, 0, (size_t)cB * cH * sizeof(float), stream);
  hipMemsetAsync(hdecB, 0, (size_t)cB * cH * sizeof(short), stream);
  for (int t = 0; t < cTp; ++t) {
    int yidx = 4 + 5 * t;  // idx = [4,9,...,44]
    gemm_bf16_nt<<<dim3(cB / 128, cG / 128), 256, 0, stream>>>(
        xencB + t * cH, cTp * cH, 512, hdecB, cH,
        WdecB, cKD, bdec, Gt, nullptr, cG, cKD, 1.0f);
    lstm_update<<<((long)cB * cH + 255) / 256, 256, 0, stream>>>(
        Gt, cdec, hdecB, nullptr, 0, y, yidx, wy);
  }

  // 5. q, k, v projections (bf16 out)
  gemm_bf16_nt<<<dim3(cB / 128, cH / 128), 256, 0, stream>>>(
      hdecB, cH, cH, nullptr, 0, wqB, cH, nullptr, nullptr, qB, cH, cH, 1.0f);
  gemm_bf16_nt<<<dim3(cB / 128, cH / 128), 256, 0, stream>>>(
      hdecB, cH, cH, nullptr, 0, wkB, cH, nullptr, nullptr, kB, cH, cH, 1.0f);
  gemm_bf16_nt<<<dim3(cB / 128, cH / 128), 256, 0, stream>>>(
      hdecB, cH, cH, nullptr, 0, wvB, cH, nullptr, nullptr, vB, cH, cH, 1.0f);

  // 6. z = q@k^T / sqrt(H)  (bf16 out)
  const float alpha = 1.0f / sqrtf((float)cH);
  gemm_bf16_nt<<<dim3(cB / 128, cB / 128), 256, 0, stream>>>(
      qB, cH, cH, nullptr, 0, kB, cH, nullptr, nullptr, zB, cB, cH, alpha);

  // 7. softmax rows in place (z -> beta)
  softmax_b<<<cB, 256, 0, stream>>>(zB);

  // 8. st = beta @ v (via bf16 v^T)
  transpose_v16<<<dim3(cB / 32, cH / 32), 256, 0, stream>>>(vB, vT);
  gemm_bf16_nt<<<dim3(cB / 128, cH / 128), 256, 0, stream>>>(
      zB, cB, cB, nullptr, 0, vT, cB, nullptr, st, nullptr, cH, cB, 1.0f);

  // 9. final sigmoid head
  final_kernel<<<cB / 4, 256, 0, stream>>>(st, ln_w, ln_b, out);
}